// Round 5
// baseline (593.601 us; speedup 1.0000x reference)
//
#include <hip/hip_runtime.h>
#include <hip/hip_bf16.h>
#include <hip/hip_fp16.h>

#define TPB 256

typedef _Float16 half8 __attribute__((ext_vector_type(8)));
typedef float f32x4 __attribute__((ext_vector_type(4)));

// ---------------- fused prep: edge count (+pos), feat1 (unscaled), W2->fp16 ------

__global__ void fused_prep(const int* __restrict__ ei, int* __restrict__ cnt,
                           int* __restrict__ pos,
                           const float* __restrict__ x, const float* __restrict__ Wc1,
                           const float* __restrict__ Wv1, __half* __restrict__ tbuf,
                           const float* __restrict__ Wc2, const float* __restrict__ Wv2,
                           __half* __restrict__ Wch, __half* __restrict__ Wvh2,
                           int N, int E, int nbE, int nbF) {
    __shared__ float xt[16][16];
    int bid = blockIdx.x;
    int t = threadIdx.x;
    if (bid < nbE) {
        // edge pass 1: per-dst arrival rank + degree count
        int e = bid * TPB + t;
        if (e < E) {
            int d = ei[E + e];
            pos[e] = atomicAdd(&cnt[d], 1);
        }
    } else if (bid < nbE + nbF) {
        // feat1: t1[i,0:128]=x@Wc1^T, t1[i,128:256]=x@Wv1^T  (NOT dis-scaled)
        int n0 = (bid - nbE) * 16;
        {
            int n = t >> 4, k = t & 15;
            int node = n0 + n;
            xt[n][k] = (node < N) ? x[node * 16 + k] : 0.f;
        }
        const float* wrow = (t < 128) ? (Wc1 + t * 16) : (Wv1 + (t - 128) * 16);
        float4 w0 = *(const float4*)(wrow + 0);
        float4 w1 = *(const float4*)(wrow + 4);
        float4 w2 = *(const float4*)(wrow + 8);
        float4 w3 = *(const float4*)(wrow + 12);
        __syncthreads();
        for (int n = 0; n < 16; ++n) {
            int node = n0 + n;
            if (node >= N) break;
            const float* xr = xt[n];
            float s = w0.x * xr[0] + w0.y * xr[1] + w0.z * xr[2] + w0.w * xr[3]
                    + w1.x * xr[4] + w1.y * xr[5] + w1.z * xr[6] + w1.w * xr[7]
                    + w2.x * xr[8] + w2.y * xr[9] + w2.z * xr[10] + w2.w * xr[11]
                    + w3.x * xr[12] + w3.y * xr[13] + w3.z * xr[14] + w3.w * xr[15];
            tbuf[(size_t)node * 256 + t] = __float2half_rn(s);
        }
    } else {
        int i = (bid - nbE - nbF) * TPB + t;
        if (i < 128 * 128) {
            Wch[i]  = __float2half_rn(Wc2[i]);
            Wvh2[i] = __float2half_rn(Wv2[i]);
        }
    }
}

// ---------------- scan: cnt -> rowptr (exclusive), dis = rsqrt(deg+1) ------------

__global__ void scan_a(const int* __restrict__ cnt, int* __restrict__ rowptr,
                       float* __restrict__ dis, int* __restrict__ bsum, int N) {
    __shared__ int sd[TPB];
    int t = threadIdx.x;
    int i = blockIdx.x * TPB + t;
    int v = (i < N) ? cnt[i] : 0;
    if (i < N) dis[i] = rsqrtf((float)(v + 1));
    sd[t] = v;
    __syncthreads();
    for (int off = 1; off < TPB; off <<= 1) {
        int x = 0;
        if (t >= off) x = sd[t - off];
        __syncthreads();
        sd[t] += x;
        __syncthreads();
    }
    if (i < N) rowptr[i] = sd[t] - v;
    if (t == TPB - 1) bsum[blockIdx.x] = sd[t];
}

__global__ void scan_b(int* __restrict__ bsum, int nb) {
    __shared__ int sd[TPB];
    int t = threadIdx.x;
    int v = (t < nb) ? bsum[t] : 0;
    sd[t] = v;
    __syncthreads();
    for (int off = 1; off < TPB; off <<= 1) {
        int x = 0;
        if (t >= off) x = sd[t - off];
        __syncthreads();
        sd[t] += x;
        __syncthreads();
    }
    if (t < nb) bsum[t] = sd[t] - v;
}

__global__ void scan_c(int* __restrict__ rowptr, const int* __restrict__ bsum,
                       int N, int E) {
    int i = blockIdx.x * TPB + threadIdx.x;
    if (i < N) rowptr[i] += bsum[blockIdx.x];
    if (i == 0) rowptr[N] = E;
}

// ---------------- CSR fill (atomic-free): rec[e] = {src, dis[src]} ---------------

__global__ void fill_csr(const int* __restrict__ ei, const int* __restrict__ rowptr,
                         const int* __restrict__ pos, const float* __restrict__ dis,
                         unsigned long long* __restrict__ rec, int E) {
    int e = blockIdx.x * TPB + threadIdx.x;
    if (e >= E) return;
    int s = ei[e], d = ei[E + e];
    int p = rowptr[d] + pos[e];
    unsigned long long r = ((unsigned long long)__float_as_uint(dis[s]) << 32)
                         | (unsigned)s;
    rec[p] = r;
}

// ---------------- sliced aggregation core ----------------------------------------
// blockIdx%8 = feature slice (64 B of each 512 B row) -> one slice per XCD so the
// gather working set (3.2 MB) is L2-resident. Wave = one (node, slice); 8 lane-
// groups of 8 lanes each handle 8 edges in flight (8 B = 4 fp16 per lane). Edge
// records {src, dis[src]} are streamed non-temporally with 1-batch prefetch.

#define AGG_GATHER(EPILOG)                                                         \
    int slice = blockIdx.x & 7;                                                    \
    int chunk = blockIdx.x >> 3;                                                   \
    int node = chunk * 16 + (threadIdx.x >> 6);                                    \
    if (node >= N) return;                                                         \
    int lane = threadIdx.x & 63;                                                   \
    int j = lane >> 3, l = lane & 7;                                               \
    int soff = slice * 8 + l;                                                      \
    int start = rowptr[node], end = rowptr[node + 1];                              \
    float dn = dis[node];                                                          \
    float ax = 0.f, ay = 0.f, az = 0.f, aw = 0.f;                                  \
    if (j == 0) {                                                                  \
        uint2 m = tin[(size_t)node * 64 + soff];                                   \
        float2 f0 = __half22float2(*reinterpret_cast<const __half2*>(&m.x));       \
        float2 f1 = __half22float2(*reinterpret_cast<const __half2*>(&m.y));       \
        ax = dn * f0.x; ay = dn * f0.y; az = dn * f1.x; aw = dn * f1.y;            \
    }                                                                              \
    int e = start + j;                                                             \
    unsigned long long r = 0ull;                                                   \
    if (e < end) r = __builtin_nontemporal_load(rec + e);                          \
    for (int e0 = start; e0 < end; e0 += 8) {                                      \
        int src = (int)(unsigned)r;                                                \
        float ds = __uint_as_float((unsigned)(r >> 32));                           \
        int en = e + 8;                                                            \
        unsigned long long rn = 0ull;                                              \
        if (en < end) rn = __builtin_nontemporal_load(rec + en);                   \
        uint2 m = tin[(size_t)src * 64 + soff];                                    \
        float2 f0 = __half22float2(*reinterpret_cast<const __half2*>(&m.x));       \
        float2 f1 = __half22float2(*reinterpret_cast<const __half2*>(&m.y));       \
        ax = fmaf(ds, f0.x, ax); ay = fmaf(ds, f0.y, ay);                          \
        az = fmaf(ds, f1.x, az); aw = fmaf(ds, f1.y, aw);                          \
        r = rn; e = en;                                                            \
    }                                                                              \
    for (int off = 32; off >= 8; off >>= 1) {                                      \
        ax += __shfl_down(ax, off, 64);                                            \
        ay += __shfl_down(ay, off, 64);                                            \
        az += __shfl_down(az, off, 64);                                            \
        aw += __shfl_down(aw, off, 64);                                            \
    }                                                                              \
    if (j == 0) { EPILOG }

__global__ __launch_bounds__(1024)
void agg1_s(const uint2* __restrict__ tin, const int* __restrict__ rowptr,
            const unsigned long long* __restrict__ rec, const float* __restrict__ dis,
            const float* __restrict__ bc, const float* __restrict__ bv,
            uint2* __restrict__ hout, int N) {
    AGG_GATHER(
        const float* bp_ = (slice < 4) ? (bc + slice * 32 + l * 4)
                                       : (bv + (slice - 4) * 32 + l * 4);
        float4 b = *(const float4*)bp_;
        __half2 h0 = __floats2half2_rn(fmaxf(fmaf(dn, ax, b.x), 0.f),
                                       fmaxf(fmaf(dn, ay, b.y), 0.f));
        __half2 h1 = __floats2half2_rn(fmaxf(fmaf(dn, az, b.z), 0.f),
                                       fmaxf(fmaf(dn, aw, b.w), 0.f));
        uint2 o;
        o.x = *reinterpret_cast<unsigned*>(&h0);
        o.y = *reinterpret_cast<unsigned*>(&h1);
        hout[(size_t)node * 64 + soff] = o;
    )
}

__global__ __launch_bounds__(1024)
void agg2_s(const uint2* __restrict__ tin, const int* __restrict__ rowptr,
            const unsigned long long* __restrict__ rec, const float* __restrict__ dis,
            const float* __restrict__ bc, const float* __restrict__ bv,
            const float* __restrict__ Wp, const float* __restrict__ bp,
            const float* __restrict__ Wvh, const float* __restrict__ bvh,
            float* __restrict__ outm, float* __restrict__ outv, int N) {
    AGG_GATHER(
        const float* bp_ = (slice < 4) ? (bc + slice * 32 + l * 4)
                                       : (bv + (slice - 4) * 32 + l * 4);
        float4 b = *(const float4*)bp_;
        float hx = fmaxf(fmaf(dn, ax, b.x), 0.f);
        float hy = fmaxf(fmaf(dn, ay, b.y), 0.f);
        float hz = fmaxf(fmaf(dn, az, b.z), 0.f);
        float hw = fmaxf(fmaf(dn, aw, b.w), 0.f);
        const float* wp_ = (slice < 4) ? (Wp + slice * 32 + l * 4)
                                       : (Wvh + (slice - 4) * 32 + l * 4);
        float4 w = *(const float4*)wp_;
        float p = hx * w.x + hy * w.y + hz * w.z + hw * w.w;
        p += __shfl_down(p, 4, 64);
        p += __shfl_down(p, 2, 64);
        p += __shfl_down(p, 1, 64);
        if (l == 0) {
            if (slice == 0) p += bp[0];
            if (slice == 4) p += bvh[0];
            float* dst = (slice < 4) ? (outm + node) : (outv + node);
            atomicAdd(dst, p);
        }
    )
}

// ---------------- layer 2 GEMM via MFMA: t2 = h1 @ W^T (unscaled), fp16 ----------

__global__ __launch_bounds__(256)
void feat2(const __half* __restrict__ h, const __half* __restrict__ Wc,
           const __half* __restrict__ Wv, __half* __restrict__ tout, int N) {
    int lane = threadIdx.x & 63;
    int wave = threadIdx.x >> 6;
    int quad = lane >> 4, l16 = lane & 15;
    int n0 = blockIdx.x * 64 + wave * 16;
    int br = blockIdx.y;                       // 0 policy, 1 value
    const _Float16* W = (const _Float16*)(br ? Wv : Wc);
    int koff = br * 128;

    const _Float16* arow = (const _Float16*)h + (size_t)(n0 + l16) * 256 + koff + quad * 8;
    half8 a0 = *(const half8*)(arow + 0);
    half8 a1 = *(const half8*)(arow + 32);
    half8 a2 = *(const half8*)(arow + 64);
    half8 a3 = *(const half8*)(arow + 96);

    _Float16* to = (_Float16*)tout;
#pragma unroll
    for (int jj = 0; jj < 8; ++jj) {
        const _Float16* wrow = W + (size_t)(jj * 16 + l16) * 128 + quad * 8;
        half8 b0 = *(const half8*)(wrow + 0);
        half8 b1 = *(const half8*)(wrow + 32);
        half8 b2 = *(const half8*)(wrow + 64);
        half8 b3 = *(const half8*)(wrow + 96);
        f32x4 acc = {0.f, 0.f, 0.f, 0.f};
        acc = __builtin_amdgcn_mfma_f32_16x16x32_f16(a0, b0, acc, 0, 0, 0);
        acc = __builtin_amdgcn_mfma_f32_16x16x32_f16(a1, b1, acc, 0, 0, 0);
        acc = __builtin_amdgcn_mfma_f32_16x16x32_f16(a2, b2, acc, 0, 0, 0);
        acc = __builtin_amdgcn_mfma_f32_16x16x32_f16(a3, b3, acc, 0, 0, 0);
        int fo = koff + jj * 16 + l16;
#pragma unroll
        for (int r = 0; r < 4; ++r) {
            int node = n0 + quad * 4 + r;
            if (node < N)
                to[(size_t)node * 256 + fo] = (_Float16)acc[r];
        }
    }
}

// ---------------- launch ---------------------------------------------------------

extern "C" void kernel_launch(void* const* d_in, const int* in_sizes, int n_in,
                              void* d_out, int out_size, void* d_ws, size_t ws_size,
                              hipStream_t stream) {
    const float* x   = (const float*)d_in[0];
    const int*   ei  = (const int*)  d_in[1];
    const float* Wc1 = (const float*)d_in[2];
    const float* bc1 = (const float*)d_in[3];
    const float* Wc2 = (const float*)d_in[4];
    const float* bc2 = (const float*)d_in[5];
    const float* Wp  = (const float*)d_in[6];
    const float* bp  = (const float*)d_in[7];
    const float* Wv1 = (const float*)d_in[8];
    const float* bv1 = (const float*)d_in[9];
    const float* Wv2 = (const float*)d_in[10];
    const float* bv2 = (const float*)d_in[11];
    const float* Wvh = (const float*)d_in[12];
    const float* bvh = (const float*)d_in[13];

    const int N = in_sizes[0] / 16;   // 50000
    const int E = in_sizes[1] / 2;    // 800000
    const int Npad = (N + 63) & ~63;

    size_t off = 0;
    auto alloc = [&](size_t bytes) -> void* {
        void* p = (char*)d_ws + off;
        off += (bytes + 255) & ~(size_t)255;
        return p;
    };
    int*    cnt    = (int*)alloc((size_t)N * sizeof(int));
    int*    pos    = (int*)alloc((size_t)E * sizeof(int));
    int*    rowptr = (int*)alloc((size_t)(N + 1) * sizeof(int));
    int*    bsum   = (int*)alloc(256 * sizeof(int));
    float*  dis    = (float*)alloc((size_t)Npad * sizeof(float));
    unsigned long long* rec = (unsigned long long*)alloc((size_t)E * 8); // 6.4 MB
    __half* Wch    = (__half*)alloc(128 * 128 * sizeof(__half));
    __half* Wvh2   = (__half*)alloc(128 * 128 * sizeof(__half));
    __half* tbuf   = (__half*)alloc((size_t)Npad * 256 * sizeof(__half)); // 25.6 MB
    __half* hbuf   = (__half*)alloc((size_t)Npad * 256 * sizeof(__half)); // 25.6 MB

    float* outm = (float*)d_out;
    float* outv = outm + N;

    const int nbE = (E + TPB - 1) / TPB;      // 3125
    const int nbN = (N + TPB - 1) / TPB;      // 196
    const int nbF = (N + 15) / 16;            // 3125

    (void)hipMemsetAsync(cnt, 0, (size_t)N * sizeof(int), stream);
    (void)hipMemsetAsync(d_out, 0, (size_t)2 * N * sizeof(float), stream);

    fused_prep<<<nbE + nbF + 64, TPB, 0, stream>>>(ei, cnt, pos, x, Wc1, Wv1, tbuf,
                                                   Wc2, Wv2, Wch, Wvh2,
                                                   N, E, nbE, nbF);
    scan_a<<<nbN, TPB, 0, stream>>>(cnt, rowptr, dis, bsum, N);
    scan_b<<<1, TPB, 0, stream>>>(bsum, nbN);
    scan_c<<<nbN, TPB, 0, stream>>>(rowptr, bsum, N, E);
    fill_csr<<<nbE, TPB, 0, stream>>>(ei, rowptr, pos, dis, rec, E);

    const int gridAgg = ((N + 15) / 16) * 8;  // slice = blockIdx % 8 -> XCD
    agg1_s<<<gridAgg, 1024, 0, stream>>>((const uint2*)tbuf, rowptr, rec, dis,
                                         bc1, bv1, (uint2*)hbuf, N);
    feat2<<<dim3((N + 63) / 64, 2), TPB, 0, stream>>>(hbuf, Wch, Wvh2, tbuf, N);
    agg2_s<<<gridAgg, 1024, 0, stream>>>((const uint2*)tbuf, rowptr, rec, dis,
                                         bc2, bv2, Wp, bp, Wvh, bvh,
                                         outm, outv, N);
}

// Round 6
// 311.399 us; speedup vs baseline: 1.9062x; 1.9062x over previous
//
#include <hip/hip_runtime.h>
#include <hip/hip_bf16.h>
#include <hip/hip_fp16.h>

#define TPB 256

typedef _Float16 half8 __attribute__((ext_vector_type(8)));
typedef float f32x4 __attribute__((ext_vector_type(4)));
typedef unsigned long long ull;

// ---------------- fused prep: edge count (+pos), feat1 (unscaled), W2->fp16 ------

__global__ void fused_prep(const int* __restrict__ ei, int* __restrict__ cnt,
                           int* __restrict__ pos,
                           const float* __restrict__ x, const float* __restrict__ Wc1,
                           const float* __restrict__ Wv1, __half* __restrict__ tbuf,
                           const float* __restrict__ Wc2, const float* __restrict__ Wv2,
                           __half* __restrict__ Wch, __half* __restrict__ Wvh2,
                           int N, int E, int nbE, int nbF) {
    __shared__ float xt[16][16];
    int bid = blockIdx.x;
    int t = threadIdx.x;
    if (bid < nbE) {
        // edge pass 1: per-dst arrival rank + degree count
        int e = bid * TPB + t;
        if (e < E) {
            int d = ei[E + e];
            pos[e] = atomicAdd(&cnt[d], 1);
        }
    } else if (bid < nbE + nbF) {
        // feat1: t1[i,0:128]=x@Wc1^T, t1[i,128:256]=x@Wv1^T  (NOT dis-scaled)
        int n0 = (bid - nbE) * 16;
        {
            int n = t >> 4, k = t & 15;
            int node = n0 + n;
            xt[n][k] = (node < N) ? x[node * 16 + k] : 0.f;
        }
        const float* wrow = (t < 128) ? (Wc1 + t * 16) : (Wv1 + (t - 128) * 16);
        float4 w0 = *(const float4*)(wrow + 0);
        float4 w1 = *(const float4*)(wrow + 4);
        float4 w2 = *(const float4*)(wrow + 8);
        float4 w3 = *(const float4*)(wrow + 12);
        __syncthreads();
        for (int n = 0; n < 16; ++n) {
            int node = n0 + n;
            if (node >= N) break;
            const float* xr = xt[n];
            float s = w0.x * xr[0] + w0.y * xr[1] + w0.z * xr[2] + w0.w * xr[3]
                    + w1.x * xr[4] + w1.y * xr[5] + w1.z * xr[6] + w1.w * xr[7]
                    + w2.x * xr[8] + w2.y * xr[9] + w2.z * xr[10] + w2.w * xr[11]
                    + w3.x * xr[12] + w3.y * xr[13] + w3.z * xr[14] + w3.w * xr[15];
            tbuf[(size_t)node * 256 + t] = __float2half_rn(s);
        }
    } else {
        int i = (bid - nbE - nbF) * TPB + t;
        if (i < 128 * 128) {
            Wch[i]  = __float2half_rn(Wc2[i]);
            Wvh2[i] = __float2half_rn(Wv2[i]);
        }
    }
}

// ---------------- single-kernel scan (decoupled lookback, 13 co-resident blocks) -
// rowptr = exclusive prefix of cnt; dis = rsqrt(cnt+1); rowptr[N] = E.
// flags[b] publishes (inclusive prefix through block b) + 1; 0 = not ready.

#define SCAN_T 1024
#define SCAN_PER 4

__global__ __launch_bounds__(1024)
void scan_lookback(const int* __restrict__ cnt, int* __restrict__ rowptr,
                   float* __restrict__ dis, int* __restrict__ flags,
                   int N, int E) {
    __shared__ int sd[SCAN_T];
    __shared__ int s_prev;
    int t = threadIdx.x, b = blockIdx.x;
    int base = b * (SCAN_T * SCAN_PER) + t * SCAN_PER;
    int v[SCAN_PER];
    int s = 0;
#pragma unroll
    for (int k = 0; k < SCAN_PER; ++k) {
        int i = base + k;
        v[k] = (i < N) ? cnt[i] : 0;
        s += v[k];
    }
    sd[t] = s;
    __syncthreads();
    for (int off = 1; off < SCAN_T; off <<= 1) {
        int x = 0;
        if (t >= off) x = sd[t - off];
        __syncthreads();
        sd[t] += x;
        __syncthreads();
    }
    int excl = sd[t] - s;                       // exclusive within block
    if (t == 0) {
        int prev = 0;
        if (b > 0) {
            int f;
            while ((f = __hip_atomic_load(flags + b - 1, __ATOMIC_ACQUIRE,
                                          __HIP_MEMORY_SCOPE_AGENT)) == 0) {}
            prev = f - 1;
        }
        __hip_atomic_store(flags + b, prev + sd[SCAN_T - 1] + 1,
                           __ATOMIC_RELEASE, __HIP_MEMORY_SCOPE_AGENT);
        s_prev = prev;
    }
    __syncthreads();
    int run = s_prev + excl;
#pragma unroll
    for (int k = 0; k < SCAN_PER; ++k) {
        int i = base + k;
        if (i < N) {
            rowptr[i] = run;
            dis[i] = rsqrtf((float)(v[k] + 1));
            run += v[k];
        }
    }
    if (b == 0 && t == 0) rowptr[N] = E;
}

// ---------------- CSR fill (atomic-free): rec[e] = {dis[src] : src} --------------

__global__ void fill_csr(const int* __restrict__ ei, const int* __restrict__ rowptr,
                         const int* __restrict__ pos, const float* __restrict__ dis,
                         ull* __restrict__ rec, int E) {
    int e = blockIdx.x * TPB + threadIdx.x;
    if (e >= E) return;
    int s = ei[e], d = ei[E + e];
    int p = rowptr[d] + pos[e];
    rec[p] = ((ull)__float_as_uint(dis[s]) << 32) | (unsigned)s;
}

// ---------------- fp16 helpers ---------------------------------------------------

__device__ __forceinline__ float4 h4_to_f4(uint2 m) {
    float2 f0 = __half22float2(*reinterpret_cast<const __half2*>(&m.x));
    float2 f1 = __half22float2(*reinterpret_cast<const __half2*>(&m.y));
    return make_float4(f0.x, f0.y, f1.x, f1.y);
}

// ---------------- agg1: h1[i] = relu(dn*(sum_s ds*t[s] + dn*t[i]) + b), fp16 -----
// one wave per node; lane l holds feats 4l..4l+3 (8 B); 4 edges in flight

__global__ void agg1(const uint2* __restrict__ tin, const int* __restrict__ rowptr,
                     const ull* __restrict__ rec, const float* __restrict__ dis,
                     const float* __restrict__ bc, const float* __restrict__ bv,
                     uint2* __restrict__ hout, int N) {
    int wid = blockIdx.x * (blockDim.x >> 6) + (threadIdx.x >> 6);
    if (wid >= N) return;
    int lane = threadIdx.x & 63;
    float dn = dis[wid];
    float4 self = h4_to_f4(tin[(size_t)wid * 64 + lane]);
    float4 acc = make_float4(dn * self.x, dn * self.y, dn * self.z, dn * self.w);
    int e = rowptr[wid], end = rowptr[wid + 1];
    for (; e + 3 < end; e += 4) {
        ull r0 = rec[e], r1 = rec[e + 1], r2 = rec[e + 2], r3 = rec[e + 3];
        float4 f0 = h4_to_f4(tin[(size_t)(unsigned)r0 * 64 + lane]);
        float4 f1 = h4_to_f4(tin[(size_t)(unsigned)r1 * 64 + lane]);
        float4 f2 = h4_to_f4(tin[(size_t)(unsigned)r2 * 64 + lane]);
        float4 f3 = h4_to_f4(tin[(size_t)(unsigned)r3 * 64 + lane]);
        float d0 = __uint_as_float((unsigned)(r0 >> 32));
        float d1 = __uint_as_float((unsigned)(r1 >> 32));
        float d2 = __uint_as_float((unsigned)(r2 >> 32));
        float d3 = __uint_as_float((unsigned)(r3 >> 32));
        acc.x = fmaf(d0, f0.x, fmaf(d1, f1.x, fmaf(d2, f2.x, fmaf(d3, f3.x, acc.x))));
        acc.y = fmaf(d0, f0.y, fmaf(d1, f1.y, fmaf(d2, f2.y, fmaf(d3, f3.y, acc.y))));
        acc.z = fmaf(d0, f0.z, fmaf(d1, f1.z, fmaf(d2, f2.z, fmaf(d3, f3.z, acc.z))));
        acc.w = fmaf(d0, f0.w, fmaf(d1, f1.w, fmaf(d2, f2.w, fmaf(d3, f3.w, acc.w))));
    }
    for (; e < end; ++e) {
        ull r = rec[e];
        float4 f = h4_to_f4(tin[(size_t)(unsigned)r * 64 + lane]);
        float ds = __uint_as_float((unsigned)(r >> 32));
        acc.x = fmaf(ds, f.x, acc.x); acc.y = fmaf(ds, f.y, acc.y);
        acc.z = fmaf(ds, f.z, acc.z); acc.w = fmaf(ds, f.w, acc.w);
    }
    int f = lane * 4;
    float4 b = (f < 128) ? *(const float4*)(bc + f) : *(const float4*)(bv + f - 128);
    __half2 h0 = __floats2half2_rn(fmaxf(fmaf(dn, acc.x, b.x), 0.f),
                                   fmaxf(fmaf(dn, acc.y, b.y), 0.f));
    __half2 h1 = __floats2half2_rn(fmaxf(fmaf(dn, acc.z, b.z), 0.f),
                                   fmaxf(fmaf(dn, acc.w, b.w), 0.f));
    uint2 o;
    o.x = *reinterpret_cast<unsigned*>(&h0);
    o.y = *reinterpret_cast<unsigned*>(&h1);
    hout[(size_t)wid * 64 + lane] = o;
}

// ---------------- agg2 + proj fused ----------------------------------------------
// policy head = lanes 0..31 (feats 0..127), value head = lanes 32..63

__global__ void agg2(const uint2* __restrict__ tin, const int* __restrict__ rowptr,
                     const ull* __restrict__ rec, const float* __restrict__ dis,
                     const float* __restrict__ bc, const float* __restrict__ bv,
                     const float* __restrict__ Wp, const float* __restrict__ bp,
                     const float* __restrict__ Wvh, const float* __restrict__ bvh,
                     float* __restrict__ outm, float* __restrict__ outv, int N) {
    int wid = blockIdx.x * (blockDim.x >> 6) + (threadIdx.x >> 6);
    if (wid >= N) return;
    int lane = threadIdx.x & 63;
    float dn = dis[wid];
    float4 self = h4_to_f4(tin[(size_t)wid * 64 + lane]);
    float4 acc = make_float4(dn * self.x, dn * self.y, dn * self.z, dn * self.w);
    int e = rowptr[wid], end = rowptr[wid + 1];
    for (; e + 3 < end; e += 4) {
        ull r0 = rec[e], r1 = rec[e + 1], r2 = rec[e + 2], r3 = rec[e + 3];
        float4 f0 = h4_to_f4(tin[(size_t)(unsigned)r0 * 64 + lane]);
        float4 f1 = h4_to_f4(tin[(size_t)(unsigned)r1 * 64 + lane]);
        float4 f2 = h4_to_f4(tin[(size_t)(unsigned)r2 * 64 + lane]);
        float4 f3 = h4_to_f4(tin[(size_t)(unsigned)r3 * 64 + lane]);
        float d0 = __uint_as_float((unsigned)(r0 >> 32));
        float d1 = __uint_as_float((unsigned)(r1 >> 32));
        float d2 = __uint_as_float((unsigned)(r2 >> 32));
        float d3 = __uint_as_float((unsigned)(r3 >> 32));
        acc.x = fmaf(d0, f0.x, fmaf(d1, f1.x, fmaf(d2, f2.x, fmaf(d3, f3.x, acc.x))));
        acc.y = fmaf(d0, f0.y, fmaf(d1, f1.y, fmaf(d2, f2.y, fmaf(d3, f3.y, acc.y))));
        acc.z = fmaf(d0, f0.z, fmaf(d1, f1.z, fmaf(d2, f2.z, fmaf(d3, f3.z, acc.z))));
        acc.w = fmaf(d0, f0.w, fmaf(d1, f1.w, fmaf(d2, f2.w, fmaf(d3, f3.w, acc.w))));
    }
    for (; e < end; ++e) {
        ull r = rec[e];
        float4 f = h4_to_f4(tin[(size_t)(unsigned)r * 64 + lane]);
        float ds = __uint_as_float((unsigned)(r >> 32));
        acc.x = fmaf(ds, f.x, acc.x); acc.y = fmaf(ds, f.y, acc.y);
        acc.z = fmaf(ds, f.z, acc.z); acc.w = fmaf(ds, f.w, acc.w);
    }
    int f = lane * 4;
    float4 b = (f < 128) ? *(const float4*)(bc + f) : *(const float4*)(bv + f - 128);
    float hx = fmaxf(fmaf(dn, acc.x, b.x), 0.f);
    float hy = fmaxf(fmaf(dn, acc.y, b.y), 0.f);
    float hz = fmaxf(fmaf(dn, acc.z, b.z), 0.f);
    float hw = fmaxf(fmaf(dn, acc.w, b.w), 0.f);
    const float* wptr = (lane < 32) ? (Wp + lane * 4) : (Wvh + (lane - 32) * 4);
    float4 w = *(const float4*)wptr;
    float p = hx * w.x + hy * w.y + hz * w.z + hw * w.w;
    for (int off = 16; off; off >>= 1) p += __shfl_down(p, off, 32);
    if (lane == 0)  outm[wid] = p + bp[0];
    if (lane == 32) outv[wid] = p + bvh[0];
}

// ---------------- layer 2 GEMM via MFMA: t2 = h1 @ W^T (unscaled), fp16 ----------

__global__ __launch_bounds__(256)
void feat2(const __half* __restrict__ h, const __half* __restrict__ Wc,
           const __half* __restrict__ Wv, __half* __restrict__ tout, int N) {
    int lane = threadIdx.x & 63;
    int wave = threadIdx.x >> 6;
    int quad = lane >> 4, l16 = lane & 15;
    int n0 = blockIdx.x * 64 + wave * 16;
    int br = blockIdx.y;                       // 0 policy, 1 value
    const _Float16* W = (const _Float16*)(br ? Wv : Wc);
    int koff = br * 128;

    const _Float16* arow = (const _Float16*)h + (size_t)(n0 + l16) * 256 + koff + quad * 8;
    half8 a0 = *(const half8*)(arow + 0);
    half8 a1 = *(const half8*)(arow + 32);
    half8 a2 = *(const half8*)(arow + 64);
    half8 a3 = *(const half8*)(arow + 96);

    _Float16* to = (_Float16*)tout;
#pragma unroll
    for (int jj = 0; jj < 8; ++jj) {
        const _Float16* wrow = W + (size_t)(jj * 16 + l16) * 128 + quad * 8;
        half8 b0 = *(const half8*)(wrow + 0);
        half8 b1 = *(const half8*)(wrow + 32);
        half8 b2 = *(const half8*)(wrow + 64);
        half8 b3 = *(const half8*)(wrow + 96);
        f32x4 acc = {0.f, 0.f, 0.f, 0.f};
        acc = __builtin_amdgcn_mfma_f32_16x16x32_f16(a0, b0, acc, 0, 0, 0);
        acc = __builtin_amdgcn_mfma_f32_16x16x32_f16(a1, b1, acc, 0, 0, 0);
        acc = __builtin_amdgcn_mfma_f32_16x16x32_f16(a2, b2, acc, 0, 0, 0);
        acc = __builtin_amdgcn_mfma_f32_16x16x32_f16(a3, b3, acc, 0, 0, 0);
        int fo = koff + jj * 16 + l16;
#pragma unroll
        for (int r = 0; r < 4; ++r) {
            int node = n0 + quad * 4 + r;
            if (node < N)
                to[(size_t)node * 256 + fo] = (_Float16)acc[r];
        }
    }
}

// ---------------- launch ---------------------------------------------------------

extern "C" void kernel_launch(void* const* d_in, const int* in_sizes, int n_in,
                              void* d_out, int out_size, void* d_ws, size_t ws_size,
                              hipStream_t stream) {
    const float* x   = (const float*)d_in[0];
    const int*   ei  = (const int*)  d_in[1];
    const float* Wc1 = (const float*)d_in[2];
    const float* bc1 = (const float*)d_in[3];
    const float* Wc2 = (const float*)d_in[4];
    const float* bc2 = (const float*)d_in[5];
    const float* Wp  = (const float*)d_in[6];
    const float* bp  = (const float*)d_in[7];
    const float* Wv1 = (const float*)d_in[8];
    const float* bv1 = (const float*)d_in[9];
    const float* Wv2 = (const float*)d_in[10];
    const float* bv2 = (const float*)d_in[11];
    const float* Wvh = (const float*)d_in[12];
    const float* bvh = (const float*)d_in[13];

    const int N = in_sizes[0] / 16;   // 50000
    const int E = in_sizes[1] / 2;    // 800000
    const int Npad = (N + 63) & ~63;

    size_t off = 0;
    auto alloc = [&](size_t bytes) -> void* {
        void* p = (char*)d_ws + off;
        off += (bytes + 255) & ~(size_t)255;
        return p;
    };
    int*    cnt    = (int*)alloc((size_t)(N + 64) * sizeof(int));
    int*    flags  = cnt + N;                    // 13 lookback flags, same memset
    int*    pos    = (int*)alloc((size_t)E * sizeof(int));
    int*    rowptr = (int*)alloc((size_t)(N + 1) * sizeof(int));
    float*  dis    = (float*)alloc((size_t)Npad * sizeof(float));
    ull*    rec    = (ull*)alloc((size_t)E * sizeof(ull));           // 6.4 MB
    __half* Wch    = (__half*)alloc(128 * 128 * sizeof(__half));
    __half* Wvh2   = (__half*)alloc(128 * 128 * sizeof(__half));
    __half* tbuf   = (__half*)alloc((size_t)Npad * 256 * sizeof(__half)); // 25.6 MB
    __half* hbuf   = (__half*)alloc((size_t)Npad * 256 * sizeof(__half)); // 25.6 MB

    float* outm = (float*)d_out;
    float* outv = outm + N;

    const int nbE = (E + TPB - 1) / TPB;      // 3125
    const int nbF = (N + 15) / 16;            // 3125
    const int nbS = (N + SCAN_T * SCAN_PER - 1) / (SCAN_T * SCAN_PER);  // 13

    (void)hipMemsetAsync(cnt, 0, (size_t)(N + 64) * sizeof(int), stream);

    fused_prep<<<nbE + nbF + 64, TPB, 0, stream>>>(ei, cnt, pos, x, Wc1, Wv1, tbuf,
                                                   Wc2, Wv2, Wch, Wvh2,
                                                   N, E, nbE, nbF);
    scan_lookback<<<nbS, SCAN_T, 0, stream>>>(cnt, rowptr, dis, flags, N, E);
    fill_csr<<<nbE, TPB, 0, stream>>>(ei, rowptr, pos, dis, rec, E);

    agg1<<<(N + 3) / 4, TPB, 0, stream>>>((const uint2*)tbuf, rowptr, rec, dis,
                                          bc1, bv1, (uint2*)hbuf, N);
    feat2<<<dim3((N + 63) / 64, 2), TPB, 0, stream>>>(hbuf, Wch, Wvh2, tbuf, N);
    agg2<<<(N + 3) / 4, TPB, 0, stream>>>((const uint2*)tbuf, rowptr, rec, dis,
                                          bc2, bv2, Wp, bp, Wvh, bvh,
                                          outm, outv, N);
}